// Round 11
// baseline (2540.857 us; speedup 1.0000x reference)
//
#include <hip/hip_runtime.h>
#include <math.h>

typedef __attribute__((ext_vector_type(8))) short s16x8;
typedef __attribute__((ext_vector_type(4))) float f32x4;
typedef unsigned long long ull;

constexpr float LOG2E = 1.4426950408889634f;

__device__ __forceinline__ unsigned short f2bf(float f) {
  unsigned int x = __builtin_bit_cast(unsigned int, f);
  x += 0x7fffu + ((x >> 16) & 1u);          // RNE
  return (unsigned short)(x >> 16);
}
__device__ __forceinline__ float fexp2(float x) { return __builtin_amdgcn_exp2f(x); }
__device__ __forceinline__ float frcp(float x)  { return __builtin_amdgcn_rcpf(x); }

#define MFMA16(A, B, Cc) __builtin_amdgcn_mfma_f32_16x16x32_bf16((A), (B), (Cc), 0, 0, 0)

constexpr int TT = 512;
constexpr int NB = 1024;
constexpr int CH = 2;

// ---------------------------------------------------------------------------
// ABLATION (round 2, name-tagged kernels). VM bits:
//   1 = NOSTORE : no ys stores/flag publish; consumers never wait
//   2 = NOLOAD  : no x/ys loads in the loop
//   4 = NOTRANS : gates -> cheap muls (c-chain kept live)
//  16 = NOBAR   : per-step __syncthreads removed (racy, timing-only)
// Final dispatch (VM=0) rewrites all of ys/hT -> correct output.
// ---------------------------------------------------------------------------
template <int DIN, bool FIRST, bool LAST, int VM>
__device__ __forceinline__ void scan_layer(
    unsigned short* x_s, unsigned short* h_s, float* b_s,
    const float* __restrict__ xin, unsigned short* ys,
    const float* __restrict__ Wih, const float* __restrict__ Whh,
    const float* __restrict__ bias, float* __restrict__ hT,
    int* prog_in, int* prog_out, int bblk)
{
  constexpr bool NOSTORE = (VM & 1)  != 0;
  constexpr bool NOLOAD  = (VM & 2)  != 0;
  constexpr bool NOTRANS = (VM & 4)  != 0;
  constexpr bool NOBAR   = (VM & 16) != 0;
  constexpr int KTX = DIN / 32;
  constexpr int XM  = (DIN == 32) ? 3 : 7;
  const int tid = threadIdx.x;
  const int wv = tid >> 6, ln = tid & 63, l15 = ln & 15, lg = ln >> 4;
  const int row0 = bblk * 16;
  const int sr = tid >> 5, sc = tid & 31;

  s16x8 bfx[4][KTX], bfh[4][4];
#pragma unroll
  for (int j = 0; j < 4; ++j) {
    const float scl = (j == 2) ? (2.0f * LOG2E) : (-LOG2E);
    const int n = j * 128 + wv * 16 + l15;
#pragma unroll
    for (int kt = 0; kt < KTX; ++kt) {
      s16x8 f;
#pragma unroll
      for (int e = 0; e < 8; ++e) f[e] = (short)f2bf(Wih[n * DIN + kt * 32 + lg * 8 + e] * scl);
      bfx[j][kt] = f;
    }
#pragma unroll
    for (int kt = 0; kt < 4; ++kt) {
      s16x8 f;
#pragma unroll
      for (int e = 0; e < 8; ++e) f[e] = (short)f2bf(Whh[n * 128 + kt * 32 + lg * 8 + e] * scl);
      bfh[j][kt] = f;
    }
  }
  b_s[tid] = bias[tid] * ((tid >> 7) == 2 ? 2.0f * LOG2E : -LOG2E);
  for (int i = tid; i < 2 * 16 * 128; i += 512) h_s[i] = 0;

  int avail = 0;
  if (FIRST) {
#pragma unroll
    for (int s = 0; s < CH; ++s) {
      const float v = NOLOAD ? 0.f : xin[(size_t)(row0 + sr) * (TT * 32) + s * 32 + sc];
      x_s[s * (16 * DIN) + sr * DIN + (sc ^ ((sr & XM) << 3))] = f2bf(v);
    }
  } else {
    if (!NOSTORE && !NOLOAD) {
      int f;
      do { f = __hip_atomic_load(prog_in, __ATOMIC_RELAXED, __HIP_MEMORY_SCOPE_AGENT); } while (f < 1);
      avail = f * CH;
    }
#pragma unroll
    for (int s = 0; s < CH; ++s) {
      const ull v = NOLOAD ? 0ull : __hip_atomic_load(
          (ull*)ys + ((size_t)s * (NB * 128) + (size_t)(row0 + sr) * 128 + sc * 4) / 4,
          __ATOMIC_RELAXED, __HIP_MEMORY_SCOPE_AGENT);
      *reinterpret_cast<ull*>(&x_s[s * (16 * DIN) + sr * DIN + ((sc * 4) ^ ((sr & 7) << 3))]) = v;
    }
  }
  __syncthreads();

  float cst[4] = {0.f, 0.f, 0.f, 0.f};
  const int hcol = wv * 16 + lg * 4;

  for (int t0 = 0; t0 < TT; t0 += CH) {
    const int t1 = t0 + CH;

    if (!LAST && !NOSTORE && tid == 0 && t0 > 0)
      __hip_atomic_store(prog_out, t0 / CH, __ATOMIC_RELAXED, __HIP_MEMORY_SCOPE_AGENT);

    int f_new = 0;
    if (!FIRST && !NOSTORE && !NOLOAD && t1 < TT)
      f_new = __hip_atomic_load(prog_in, __ATOMIC_RELAXED, __HIP_MEMORY_SCOPE_AGENT);

    bool prefetched = NOLOAD;
    if (!NOLOAD && t1 < TT) {
      if (FIRST) prefetched = true;
      else if (NOSTORE || avail >= t1 + CH) prefetched = true;
    }
    float xrf2[CH];
    ull   xrh2[CH];
    if (!NOLOAD && t1 < TT && prefetched) {
      if (FIRST) {
#pragma unroll
        for (int s = 0; s < CH; ++s)
          xrf2[s] = xin[(size_t)(row0 + sr) * (TT * 32) + (t1 + s) * 32 + sc];
      } else {
#pragma unroll
        for (int s = 0; s < CH; ++s)
          xrh2[s] = __hip_atomic_load(
              (ull*)ys + ((size_t)(t1 + s) * (NB * 128) + (size_t)(row0 + sr) * 128 + sc * 4) / 4,
              __ATOMIC_RELAXED, __HIP_MEMORY_SCOPE_AGENT);
      }
    }

    f32x4 gx[CH][4];
#pragma unroll
    for (int s = 0; s < CH; ++s) {
#pragma unroll
      for (int j = 0; j < 4; ++j)
        gx[s][j] = *reinterpret_cast<const f32x4*>(&b_s[j * 128 + wv * 16 + lg * 4]);
#pragma unroll
      for (int kt = 0; kt < KTX; ++kt) {
        const s16x8 xf = *reinterpret_cast<const s16x8*>(
            &x_s[s * (16 * DIN) + l15 * DIN + ((kt * 32 + lg * 8) ^ ((l15 & XM) << 3))]);
#pragma unroll
        for (int j = 0; j < 4; ++j) gx[s][j] = MFMA16(bfx[j][kt], xf, gx[s][j]);
      }
    }

    if (!NOLOAD && !NOSTORE && !FIRST && t1 < TT && !prefetched) {
      int f = f_new;
      while (f * CH < t1 + CH)
        f = __hip_atomic_load(prog_in, __ATOMIC_RELAXED, __HIP_MEMORY_SCOPE_AGENT);
      f_new = f;
      avail = f * CH;
#pragma unroll
      for (int s = 0; s < CH; ++s)
        xrh2[s] = __hip_atomic_load(
            (ull*)ys + ((size_t)(t1 + s) * (NB * 128) + (size_t)(row0 + sr) * 128 + sc * 4) / 4,
            __ATOMIC_RELAXED, __HIP_MEMORY_SCOPE_AGENT);
    }

#pragma unroll
    for (int s = 0; s < CH; ++s) {
      const int t = t0 + s;
      if (s && !NOBAR) __syncthreads();
      const unsigned short* buf = h_s + (t & 1) * (16 * 128);
      unsigned short* nbuf = h_s + ((t + 1) & 1) * (16 * 128);
      s16x8 afr[4];
#pragma unroll
      for (int kt = 0; kt < 4; ++kt)
        afr[kt] = *reinterpret_cast<const s16x8*>(
            &buf[l15 * 128 + ((kt * 32 + lg * 8) ^ ((l15 & 7) << 3))]);
      f32x4 acc[4];
#pragma unroll
      for (int j = 0; j < 4; ++j) acc[j] = gx[s][j];
#pragma unroll
      for (int kt = 0; kt < 4; ++kt)
#pragma unroll
        for (int j = 0; j < 4; ++j) acc[j] = MFMA16(bfh[j][kt], afr[kt], acc[j]);

      float hv[4];
      if constexpr (!NOTRANS) {
#pragma unroll
        for (int r = 0; r < 4; ++r) {
          const float iv = frcp(1.0f + fexp2(acc[0][r]));
          const float fv = frcp(1.0f + fexp2(acc[1][r]));
          const float gv = 1.0f - 2.0f * frcp(1.0f + fexp2(acc[2][r]));
          const float ov = frcp(1.0f + fexp2(acc[3][r]));
          const float cn = fv * cst[r] + iv * gv;
          cst[r] = cn;
          const float th = 1.0f - 2.0f * frcp(1.0f + fexp2(cn * (2.0f * LOG2E)));
          hv[r] = ov * th;
        }
      } else {
#pragma unroll
        for (int r = 0; r < 4; ++r) {
          const float cn = acc[1][r] * cst[r] + acc[0][r] * acc[2][r];
          cst[r] = cn;
          hv[r] = acc[3][r] * cn;
        }
      }
      unsigned int plo, phi;
      asm("v_cvt_pk_bf16_f32 %0, %1, %2" : "=v"(plo) : "v"(hv[0]), "v"(hv[1]));
      asm("v_cvt_pk_bf16_f32 %0, %1, %2" : "=v"(phi) : "v"(hv[2]), "v"(hv[3]));
      const ull hpack = (ull)plo | ((ull)phi << 32);

      *reinterpret_cast<ull*>(&nbuf[l15 * 128 + (hcol ^ ((l15 & 7) << 3))]) = hpack;

      if (!LAST) {
        if (!NOSTORE)
          __hip_atomic_store(
              (ull*)ys + ((size_t)t * (NB * 128) + (size_t)(row0 + l15) * 128 + hcol) / 4,
              hpack, __ATOMIC_RELAXED, __HIP_MEMORY_SCOPE_AGENT);
      } else if (t == TT - 1) {
        f32x4 o = {hv[0], hv[1], hv[2], hv[3]};
        *reinterpret_cast<f32x4*>(&hT[(row0 + l15) * 128 + hcol]) = o;
      }

      if (!NOLOAD && s == CH - 1 && t1 < TT) {
        if (FIRST) {
#pragma unroll
          for (int ss = 0; ss < CH; ++ss)
            x_s[ss * (16 * DIN) + sr * DIN + (sc ^ ((sr & XM) << 3))] = f2bf(xrf2[ss]);
        } else {
#pragma unroll
          for (int ss = 0; ss < CH; ++ss)
            *reinterpret_cast<ull*>(
                &x_s[ss * (16 * DIN) + sr * DIN + ((sc * 4) ^ ((sr & 7) << 3))]) = xrh2[ss];
        }
      }
    }

    if (!FIRST && !NOSTORE && !NOLOAD && f_new * CH > avail) avail = f_new * CH;

    if (!NOBAR) __syncthreads();
  }

  if (!LAST && !NOSTORE) {
    asm volatile("s_waitcnt vmcnt(0)" ::: "memory");
    __syncthreads();
    if (tid == 0)
      __hip_atomic_store(prog_out, TT / CH, __ATOMIC_RELAXED, __HIP_MEMORY_SCOPE_AGENT);
  }
}

template <int VM>
__device__ __forceinline__ void lstm_body(
    unsigned short* x_s, unsigned short* h_s, float* b_s,
    const float* x, unsigned short* ys,
    const float* Wih0, const float* Whh0, const float* b0,
    const float* Wih1, const float* Whh1, const float* b1,
    const float* Wih2, const float* Whh2, const float* b2,
    float* hT, int* prog)
{
  const int lay = blockIdx.x >> 6;
  const int bblk = blockIdx.x & 63;
  if (lay == 0) {
    scan_layer<32, true, false, VM>(x_s, h_s, b_s, x, ys, Wih0, Whh0, b0, nullptr,
                                    nullptr, &prog[(0 * 64 + bblk) * 16], bblk);
  } else if (lay == 1) {
    scan_layer<128, false, false, VM>(x_s, h_s, b_s, nullptr, ys, Wih1, Whh1, b1, nullptr,
                                      &prog[(0 * 64 + bblk) * 16], &prog[(1 * 64 + bblk) * 16], bblk);
  } else {
    scan_layer<128, false, true, VM>(x_s, h_s, b_s, nullptr, ys, Wih2, Whh2, b2, hT,
                                     &prog[(1 * 64 + bblk) * 16], nullptr, bblk);
  }
}

#define LSTM_KERNEL(NAME, VM)                                                   \
__global__ __launch_bounds__(512, 2) void NAME(                                 \
    const float* __restrict__ x, unsigned short* ys,                            \
    const float* __restrict__ Wih0, const float* __restrict__ Whh0, const float* __restrict__ b0, \
    const float* __restrict__ Wih1, const float* __restrict__ Whh1, const float* __restrict__ b1, \
    const float* __restrict__ Wih2, const float* __restrict__ Whh2, const float* __restrict__ b2, \
    float* __restrict__ hT, int* prog)                                          \
{                                                                               \
  __shared__ unsigned short x_s[CH * 16 * 128];                                 \
  __shared__ unsigned short h_s[2 * 16 * 128];                                  \
  __shared__ float b_s[512];                                                    \
  lstm_body<VM>(x_s, h_s, b_s, x, ys, Wih0, Whh0, b0, Wih1, Whh1, b1,           \
                Wih2, Whh2, b2, hT, prog);                                      \
}

LSTM_KERNEL(lstmA, 16)   // no barriers
LSTM_KERNEL(lstmB, 4)    // no transcendentals
LSTM_KERNEL(lstmC, 1)    // no stores/flags
LSTM_KERNEL(lstmD, 19)   // skeleton: no stores/loads/barriers
LSTM_KERNEL(lstm_fused, 0)  // production

__global__ void init_flags(int* prog) {
  prog[threadIdx.x] = 0;
  prog[threadIdx.x + 1024] = 0;
}

// ---------------------------------------------------------------------------
__global__ __launch_bounds__(256) void head_kernel(
    const float* __restrict__ hT, const float* __restrict__ eps,
    const float* __restrict__ u, const float* __restrict__ choice,
    const float* __restrict__ ln_g, const float* __restrict__ ln_b,
    const float* __restrict__ fc1_W, const float* __restrict__ fc1_b,
    const float* __restrict__ fc2_W, const float* __restrict__ fc2_b,
    const float* __restrict__ mean_W, const float* __restrict__ mean_b,
    const float* __restrict__ logvar_W, const float* __restrict__ logvar_b,
    const float* __restrict__ scale_W, const float* __restrict__ scale_b,
    const float* __restrict__ shape_W, const float* __restrict__ shape_b,
    const float* __restrict__ dec1_W, const float* __restrict__ dec1_b,
    const float* __restrict__ dec2_W, const float* __restrict__ dec2_b,
    const float* __restrict__ out_W, const float* __restrict__ out_b,
    const float* __restrict__ pi_params, float* __restrict__ out)
{
  __shared__ float s_hn[4][128];
  __shared__ float s_a[4][128];
  __shared__ float s_b2[4][64];
  __shared__ float s_z[4][64];
  __shared__ float s_d1[4][128];
  __shared__ float s_d2[4][512];

  const int tid = threadIdx.x;
  const int gr0 = blockIdx.x * 4;

  {
    const int wvr = tid >> 6, lnn = tid & 63;
    const float v0 = hT[(gr0 + wvr) * 128 + lnn];
    const float v1 = hT[(gr0 + wvr) * 128 + 64 + lnn];
    float s = v0 + v1, s2 = v0 * v0 + v1 * v1;
#pragma unroll
    for (int off = 32; off; off >>= 1) {
      s  += __shfl_xor(s, off, 64);
      s2 += __shfl_xor(s2, off, 64);
    }
    const float mu  = s * (1.f / 128.f);
    const float var = s2 * (1.f / 128.f) - mu * mu;
    const float rs  = rsqrtf(var + 1e-5f);
    s_hn[wvr][lnn]      = (v0 - mu) * rs * ln_g[lnn]      + ln_b[lnn];
    s_hn[wvr][lnn + 64] = (v1 - mu) * rs * ln_g[lnn + 64] + ln_b[lnn + 64];
  }
  __syncthreads();
#pragma unroll
  for (int p = 0; p < 2; ++p) {
    const int idx = tid + p * 256, row = idx >> 7, col = idx & 127;
    const float* w = fc1_W + col * 128;
    float a = fc1_b[col];
    for (int k = 0; k < 128; k += 4)
      a += s_hn[row][k] * w[k] + s_hn[row][k + 1] * w[k + 1] +
           s_hn[row][k + 2] * w[k + 2] + s_hn[row][k + 3] * w[k + 3];
    s_a[row][col] = fmaxf(a, 0.f);
  }
  __syncthreads();
  {
    const int row = tid >> 6, col = tid & 63;
    const float* w = fc2_W + col * 128;
    float a = fc2_b[col];
    for (int k = 0; k < 128; ++k) a += s_a[row][k] * w[k];
    s_b2[row][col] = fmaxf(a, 0.f);
  }
  __syncthreads();
  {
    const int row = tid >> 6, c = tid & 63;
    const int gr = gr0 + row;
    float am = mean_b[c], al = logvar_b[c], as_ = scale_b[c], ah = shape_b[c];
    for (int k = 0; k < 64; ++k) {
      const float hv = s_b2[row][k];
      am  += hv * mean_W[c * 64 + k];
      al  += hv * logvar_W[c * 64 + k];
      as_ += hv * scale_W[c * 64 + k];
      ah  += hv * shape_W[c * 64 + k];
    }
    const float zsc = fexp2(as_ * LOG2E);
    const float zsh = fmaxf(ah, 1e-6f);
    out[131072 + gr * 64 + c] = am;
    out[196608 + gr * 64 + c] = al;
    out[262144 + gr * 64 + c] = zsc;
    out[327680 + gr * 64 + c] = zsh;
    const float ev = eps[gr * 64 + c], uv = u[gr * 64 + c], cv = choice[gr];
    const float zg = am + ev * fexp2(0.72134752044448170f * al);
    const float p0 = pi_params[0], p1 = pi_params[1];
    const float pi0 = 1.f / (1.f + expf(p1 - p0));
    const float tq = -zsh * logf(1.f - uv);
    const float zp = zsc * frcp(zsh) * expm1f(tq);
    s_z[row][c] = (cv < pi0) ? zg : zp;
  }
  __syncthreads();
#pragma unroll
  for (int p = 0; p < 2; ++p) {
    const int idx = tid + p * 256, row = idx >> 7, col = idx & 127;
    const float* w = dec1_W + col * 64;
    float a = dec1_b[col];
    for (int k = 0; k < 64; ++k) a += s_z[row][k] * w[k];
    s_d1[row][col] = fmaxf(a, 0.f);
  }
  __syncthreads();
  for (int o = tid; o < 2000; o += 256) {
    const int row = o / 500, col = o % 500;
    const float* w = dec2_W + col * 128;
    float a = dec2_b[col];
    for (int k = 0; k < 128; ++k) a += s_d1[row][k] * w[k];
    s_d2[row][col] = fmaxf(a, 0.f);
  }
  __syncthreads();
#pragma unroll
  for (int p = 0; p < 2; ++p) {
    const int idx = tid + p * 256, row = idx >> 7, col = idx & 127;
    const float* w = out_W + col * 500;
    float a = out_b[col];
    for (int k = 0; k < 500; ++k) a += s_d2[row][k] * w[k];
    out[(gr0 + row) * 128 + col] = a;
  }
}

// ---------------------------------------------------------------------------
extern "C" void kernel_launch(void* const* d_in, const int* in_sizes, int n_in,
                              void* d_out, int out_size, void* d_ws, size_t ws_size,
                              hipStream_t stream) {
  const float* x      = (const float*)d_in[0];
  const float* eps    = (const float*)d_in[1];
  const float* u      = (const float*)d_in[2];
  const float* choice = (const float*)d_in[3];
  const float* Wih0 = (const float*)d_in[4],  *Whh0 = (const float*)d_in[5],  *b0 = (const float*)d_in[6];
  const float* Wih1 = (const float*)d_in[7],  *Whh1 = (const float*)d_in[8],  *b1 = (const float*)d_in[9];
  const float* Wih2 = (const float*)d_in[10], *Whh2 = (const float*)d_in[11], *b2 = (const float*)d_in[12];
  const float* ln_g = (const float*)d_in[13], *ln_b = (const float*)d_in[14];
  const float* fc1_W = (const float*)d_in[15], *fc1_b = (const float*)d_in[16];
  const float* fc2_W = (const float*)d_in[17], *fc2_b = (const float*)d_in[18];
  const float* mean_W = (const float*)d_in[19], *mean_b = (const float*)d_in[20];
  const float* logvar_W = (const float*)d_in[21], *logvar_b = (const float*)d_in[22];
  const float* scale_W = (const float*)d_in[23], *scale_b = (const float*)d_in[24];
  const float* shape_W = (const float*)d_in[25], *shape_b = (const float*)d_in[26];
  const float* dec1_W = (const float*)d_in[27], *dec1_b = (const float*)d_in[28];
  const float* dec2_W = (const float*)d_in[29], *dec2_b = (const float*)d_in[30];
  const float* out_W = (const float*)d_in[31], *out_b = (const float*)d_in[32];
  const float* pi_params = (const float*)d_in[33];

  unsigned short* ys = (unsigned short*)d_ws;
  float* hT  = (float*)((char*)d_ws + (size_t)512 * 1024 * 128 * 2);
  int*   prog = (int*)((char*)d_ws + (size_t)512 * 1024 * 128 * 2 + (size_t)1024 * 128 * 4);

  // ---- ablation dispatches (timing only; VM=0 rewrites everything) ----
  init_flags<<<1, 1024, 0, stream>>>(prog);
  lstmA<<<192, 512, 0, stream>>>(x, ys, Wih0, Whh0, b0, Wih1, Whh1, b1, Wih2, Whh2, b2, hT, prog);
  init_flags<<<1, 1024, 0, stream>>>(prog);
  lstmB<<<192, 512, 0, stream>>>(x, ys, Wih0, Whh0, b0, Wih1, Whh1, b1, Wih2, Whh2, b2, hT, prog);
  init_flags<<<1, 1024, 0, stream>>>(prog);
  lstmC<<<192, 512, 0, stream>>>(x, ys, Wih0, Whh0, b0, Wih1, Whh1, b1, Wih2, Whh2, b2, hT, prog);
  init_flags<<<1, 1024, 0, stream>>>(prog);
  lstmD<<<192, 512, 0, stream>>>(x, ys, Wih0, Whh0, b0, Wih1, Whh1, b1, Wih2, Whh2, b2, hT, prog);

  // ---- production ----
  init_flags<<<1, 1024, 0, stream>>>(prog);
  lstm_fused<<<192, 512, 0, stream>>>(x, ys, Wih0, Whh0, b0, Wih1, Whh1, b1, Wih2, Whh2, b2, hT, prog);
  head_kernel<<<256, 256, 0, stream>>>(hT, eps, u, choice, ln_g, ln_b,
      fc1_W, fc1_b, fc2_W, fc2_b, mean_W, mean_b, logvar_W, logvar_b,
      scale_W, scale_b, shape_W, shape_b, dec1_W, dec1_b, dec2_W, dec2_b,
      out_W, out_b, pi_params, (float*)d_out);
}

// Round 12
// 1155.942 us; speedup vs baseline: 2.1981x; 2.1981x over previous
//
#include <hip/hip_runtime.h>
#include <math.h>

typedef __attribute__((ext_vector_type(8))) short s16x8;
typedef __attribute__((ext_vector_type(4))) float f32x4;
typedef unsigned long long ull;

constexpr float LOG2E = 1.4426950408889634f;

__device__ __forceinline__ unsigned short f2bf(float f) {
  unsigned int x = __builtin_bit_cast(unsigned int, f);
  x += 0x7fffu + ((x >> 16) & 1u);          // RNE
  return (unsigned short)(x >> 16);
}
__device__ __forceinline__ float fexp2(float x) { return __builtin_amdgcn_exp2f(x); }
__device__ __forceinline__ float frcp(float x)  { return __builtin_amdgcn_rcpf(x); }

#define MFMA16(A, B, Cc) __builtin_amdgcn_mfma_f32_16x16x32_bf16((A), (B), (Cc), 0, 0, 0)

constexpr int TT = 512;
constexpr int NB = 1024;
constexpr int CH = 2;

// Shared-denominator LSTM cell (round-9 validated: absmax identical to the
// 10-trans version). 7 trans/cell. Inputs pre-scaled: i,f,o by -log2e, g by
// +2log2e.  c' = [c(1+I)(1+G) + (G-1)(1+F)] / [(1+F)(1+I)(1+G)];
// h = (E-1)/[(1+O)(E+1)], E = 2^(2log2e c'). Clamps keep products finite.
__device__ __forceinline__ float lstm_cell(float ai, float af, float ag, float ao,
                                           float& c) {
  const float F = fexp2(fminf(af, 29.f));
  const float I = fexp2(fminf(ai, 29.f));
  const float G = fexp2(fminf(ag, 29.f));
  const float O = fexp2(fminf(ao, 29.f));
  const float P   = (1.f + I) * (1.f + G);
  const float num = c * P + (G - 1.f) * (1.f + F);
  const float cn  = num * frcp((1.f + F) * P);
  c = cn;
  const float E = fexp2(fminf(cn * (2.f * LOG2E), 60.f));
  return (E - 1.f) * frcp((1.f + O) * (E + 1.f));
}

// ---------------------------------------------------------------------------
// 32 batch rows/block as TWO 16-row groups (A: +0, B: +16), 8 waves.
// Every wave runs BOTH groups' chains interleaved in its own stream with the
// SAME weight registers -> independent dep-chains overlap the LDS/trans/MFMA
// pipes that the ablation showed were being used serially (lstmA == prod).
// Sync structure identical to the 655us round-6 kernel (2 barriers/chunk).
// Grid: 32 blocks x 3 layers = 96. Flags: ys [0,F*CH) visible at MALL.
// ---------------------------------------------------------------------------
template <int DIN, bool FIRST, bool LAST>
__device__ __forceinline__ void scan_layer(
    unsigned short* x_s,                      // [CH][32][DIN] swizzled
    unsigned short* h_s,                      // [2][32][128] swizzled dbuf
    float* b_s,                               // [512] pre-scaled bias
    const float* __restrict__ xin,            // FIRST: x [B][T][32] f32
    unsigned short* ys,                       // [T][B][128] bf16 pipe (in-place)
    const float* __restrict__ Wih, const float* __restrict__ Whh,
    const float* __restrict__ bias, float* __restrict__ hT,
    int* prog_in, int* prog_out, int bblk)
{
  constexpr int KTX = DIN / 32;
  constexpr int XM  = (DIN == 32) ? 3 : 7;
  const int tid = threadIdx.x;
  const int wv = tid >> 6, ln = tid & 63, l15 = ln & 15, lg = ln >> 4;
  const int row0 = bblk * 32;
  const int swzx = (l15 & XM) << 3;           // same for rows l15 and 16+l15
  const int swzh = (l15 & 7) << 3;

  // ---- weights -> regs (bf16, pre-scaled); SHARED by both groups ----
  s16x8 bfx[4][KTX], bfh[4][4];
#pragma unroll
  for (int j = 0; j < 4; ++j) {
    const float scl = (j == 2) ? (2.0f * LOG2E) : (-LOG2E);
    const int n = j * 128 + wv * 16 + l15;
#pragma unroll
    for (int kt = 0; kt < KTX; ++kt) {
      s16x8 f;
#pragma unroll
      for (int e = 0; e < 8; ++e) f[e] = (short)f2bf(Wih[n * DIN + kt * 32 + lg * 8 + e] * scl);
      bfx[j][kt] = f;
    }
#pragma unroll
    for (int kt = 0; kt < 4; ++kt) {
      s16x8 f;
#pragma unroll
      for (int e = 0; e < 8; ++e) f[e] = (short)f2bf(Whh[n * 128 + kt * 32 + lg * 8 + e] * scl);
      bfh[j][kt] = f;
    }
  }
  b_s[tid] = bias[tid] * ((tid >> 7) == 2 ? 2.0f * LOG2E : -LOG2E);
  for (int i = tid; i < 2 * 32 * 128; i += 512) h_s[i] = 0;   // h0 = 0

  // ---- prologue: acquire + stage chunk 0 (each thread: 2 units/step) ----
  float xrf[CH][2];
  ull   xrh[CH][2];
  int avail = 0;
  if (FIRST) {
#pragma unroll
    for (int s = 0; s < CH; ++s)
#pragma unroll
      for (int p = 0; p < 2; ++p) {
        const int idx = p * 512 + tid, r = idx >> 5, c = idx & 31;
        const float v = xin[(size_t)(row0 + r) * (TT * 32) + s * 32 + c];
        x_s[s * (32 * 32) + r * 32 + (c ^ ((r & 3) << 3))] = f2bf(v);
      }
  } else {
    int f;
    do { f = __hip_atomic_load(prog_in, __ATOMIC_RELAXED, __HIP_MEMORY_SCOPE_AGENT); } while (f < 1);
    avail = f * CH;
#pragma unroll
    for (int s = 0; s < CH; ++s)
#pragma unroll
      for (int p = 0; p < 2; ++p) {
        const int idx = p * 512 + tid, r = idx >> 5, ku = idx & 31;
        const ull v = __hip_atomic_load(
            (ull*)ys + ((size_t)s * (NB * 128) + (size_t)(row0 + r) * 128 + ku * 4) / 4,
            __ATOMIC_RELAXED, __HIP_MEMORY_SCOPE_AGENT);
        *reinterpret_cast<ull*>(&x_s[s * (32 * 128) + r * 128 + ((ku * 4) ^ ((r & 7) << 3))]) = v;
      }
  }
  __syncthreads();                            // x_s + h0 + b_s visible

  float cstA[4] = {0.f, 0.f, 0.f, 0.f};
  float cstB[4] = {0.f, 0.f, 0.f, 0.f};
  const int hcol = wv * 16 + lg * 4;

  for (int t0 = 0; t0 < TT; t0 += CH) {
    const int t1 = t0 + CH;

    // ---- lagged flag publish (prev chunk's stores drained by its sync) ----
    if (!LAST && tid == 0 && t0 > 0)
      __hip_atomic_store(prog_out, t0 / CH, __ATOMIC_RELAXED, __HIP_MEMORY_SCOPE_AGENT);

    // ---- async flag read, absorbed at chunk end ----
    int f_new = 0;
    if (!FIRST && t1 < TT)
      f_new = __hip_atomic_load(prog_in, __ATOMIC_RELAXED, __HIP_MEMORY_SCOPE_AGENT);

    // ---- prefetch next chunk's input at chunk TOP (steady path) ----
    bool prefetched = false;
    if (t1 < TT) {
      if (FIRST) {
#pragma unroll
        for (int s = 0; s < CH; ++s)
#pragma unroll
          for (int p = 0; p < 2; ++p) {
            const int idx = p * 512 + tid, r = idx >> 5, c = idx & 31;
            xrf[s][p] = xin[(size_t)(row0 + r) * (TT * 32) + (t1 + s) * 32 + c];
          }
        prefetched = true;
      } else if (avail >= t1 + CH) {
#pragma unroll
        for (int s = 0; s < CH; ++s)
#pragma unroll
          for (int p = 0; p < 2; ++p) {
            const int idx = p * 512 + tid, r = idx >> 5, ku = idx & 31;
            xrh[s][p] = __hip_atomic_load(
                (ull*)ys + ((size_t)(t1 + s) * (NB * 128) + (size_t)(row0 + r) * 128 + ku * 4) / 4,
                __ATOMIC_RELAXED, __HIP_MEMORY_SCOPE_AGENT);
          }
        prefetched = true;
      }
    }

    // ---- burst: gx = bias + x@Wih^T for BOTH groups, both steps ----
    f32x4 gxA[CH][4], gxB[CH][4];
#pragma unroll
    for (int s = 0; s < CH; ++s) {
#pragma unroll
      for (int j = 0; j < 4; ++j) {
        const f32x4 bj = *reinterpret_cast<const f32x4*>(&b_s[j * 128 + wv * 16 + lg * 4]);
        gxA[s][j] = bj; gxB[s][j] = bj;
      }
#pragma unroll
      for (int kt = 0; kt < KTX; ++kt) {
        const s16x8 xfA = *reinterpret_cast<const s16x8*>(
            &x_s[s * (32 * DIN) + l15 * DIN + ((kt * 32 + lg * 8) ^ swzx)]);
        const s16x8 xfB = *reinterpret_cast<const s16x8*>(
            &x_s[s * (32 * DIN) + (16 + l15) * DIN + ((kt * 32 + lg * 8) ^ swzx)]);
#pragma unroll
        for (int j = 0; j < 4; ++j) {
          gxA[s][j] = MFMA16(bfx[j][kt], xfA, gxA[s][j]);
          gxB[s][j] = MFMA16(bfx[j][kt], xfB, gxB[s][j]);
        }
      }
    }

    // ---- slow path: flag shortfall ----
    if (!FIRST && t1 < TT && !prefetched) {
      int f = f_new;
      while (f * CH < t1 + CH)
        f = __hip_atomic_load(prog_in, __ATOMIC_RELAXED, __HIP_MEMORY_SCOPE_AGENT);
      f_new = f;
      avail = f * CH;
#pragma unroll
      for (int s = 0; s < CH; ++s)
#pragma unroll
        for (int p = 0; p < 2; ++p) {
          const int idx = p * 512 + tid, r = idx >> 5, ku = idx & 31;
          xrh[s][p] = __hip_atomic_load(
              (ull*)ys + ((size_t)(t1 + s) * (NB * 128) + (size_t)(row0 + r) * 128 + ku * 4) / 4,
              __ATOMIC_RELAXED, __HIP_MEMORY_SCOPE_AGENT);
        }
    }

    // ---- chain: CH steps, both groups interleaved per wave ----
#pragma unroll
    for (int s = 0; s < CH; ++s) {
      const int t = t0 + s;
      if (s) __syncthreads();                 // h(t) visible
      const unsigned short* buf = h_s + (t & 1) * (32 * 128);
      unsigned short* nbuf = h_s + ((t + 1) & 1) * (32 * 128);

      s16x8 afrA[4], afrB[4];
#pragma unroll
      for (int kt = 0; kt < 4; ++kt) {
        afrA[kt] = *reinterpret_cast<const s16x8*>(
            &buf[l15 * 128 + ((kt * 32 + lg * 8) ^ swzh)]);
        afrB[kt] = *reinterpret_cast<const s16x8*>(
            &buf[(16 + l15) * 128 + ((kt * 32 + lg * 8) ^ swzh)]);
      }
      f32x4 accA[4], accB[4];
#pragma unroll
      for (int j = 0; j < 4; ++j) { accA[j] = gxA[s][j]; accB[j] = gxB[s][j]; }
#pragma unroll
      for (int kt = 0; kt < 4; ++kt)
#pragma unroll
        for (int j = 0; j < 4; ++j) {
          accA[j] = MFMA16(bfh[j][kt], afrA[kt], accA[j]);
          accB[j] = MFMA16(bfh[j][kt], afrB[kt], accB[j]);
        }

      float hvA[4], hvB[4];
#pragma unroll
      for (int r = 0; r < 4; ++r) {
        hvA[r] = lstm_cell(accA[0][r], accA[1][r], accA[2][r], accA[3][r], cstA[r]);
        hvB[r] = lstm_cell(accB[0][r], accB[1][r], accB[2][r], accB[3][r], cstB[r]);
      }
      unsigned int aLo, aHi, bLo, bHi;
      asm("v_cvt_pk_bf16_f32 %0, %1, %2" : "=v"(aLo) : "v"(hvA[0]), "v"(hvA[1]));
      asm("v_cvt_pk_bf16_f32 %0, %1, %2" : "=v"(aHi) : "v"(hvA[2]), "v"(hvA[3]));
      asm("v_cvt_pk_bf16_f32 %0, %1, %2" : "=v"(bLo) : "v"(hvB[0]), "v"(hvB[1]));
      asm("v_cvt_pk_bf16_f32 %0, %1, %2" : "=v"(bHi) : "v"(hvB[2]), "v"(hvB[3]));
      const ull packA = (ull)aLo | ((ull)aHi << 32);
      const ull packB = (ull)bLo | ((ull)bHi << 32);

      *reinterpret_cast<ull*>(&nbuf[l15 * 128 + (hcol ^ swzh)]) = packA;
      *reinterpret_cast<ull*>(&nbuf[(16 + l15) * 128 + (hcol ^ swzh)]) = packB;

      if (!LAST) {
        __hip_atomic_store(
            (ull*)ys + ((size_t)t * (NB * 128) + (size_t)(row0 + l15) * 128 + hcol) / 4,
            packA, __ATOMIC_RELAXED, __HIP_MEMORY_SCOPE_AGENT);
        __hip_atomic_store(
            (ull*)ys + ((size_t)t * (NB * 128) + (size_t)(row0 + 16 + l15) * 128 + hcol) / 4,
            packB, __ATOMIC_RELAXED, __HIP_MEMORY_SCOPE_AGENT);
      } else if (t == TT - 1) {
        f32x4 oA = {hvA[0], hvA[1], hvA[2], hvA[3]};
        f32x4 oB = {hvB[0], hvB[1], hvB[2], hvB[3]};
        *reinterpret_cast<f32x4*>(&hT[(row0 + l15) * 128 + hcol]) = oA;      // f32 for LN
        *reinterpret_cast<f32x4*>(&hT[(row0 + 16 + l15) * 128 + hcol]) = oB;
      }

      // last chain step: stage next chunk's x tile before the closing sync
      if (s == CH - 1 && t1 < TT) {
        if (FIRST) {
#pragma unroll
          for (int ss = 0; ss < CH; ++ss)
#pragma unroll
            for (int p = 0; p < 2; ++p) {
              const int idx = p * 512 + tid, r = idx >> 5, c = idx & 31;
              x_s[ss * (32 * 32) + r * 32 + (c ^ ((r & 3) << 3))] = f2bf(xrf[ss][p]);
            }
        } else {
#pragma unroll
          for (int ss = 0; ss < CH; ++ss)
#pragma unroll
            for (int p = 0; p < 2; ++p) {
              const int idx = p * 512 + tid, r = idx >> 5, ku = idx & 31;
              *reinterpret_cast<ull*>(
                  &x_s[ss * (32 * 128) + r * 128 + ((ku * 4) ^ ((r & 7) << 3))]) = xrh[ss][p];
            }
        }
      }
    }

    if (!FIRST && f_new * CH > avail) avail = f_new * CH;

    __syncthreads();  // h(t0+CH) + next x_s visible; this chunk's ys stores drained
  }

  if (!LAST) {
    asm volatile("s_waitcnt vmcnt(0)" ::: "memory");
    __syncthreads();
    if (tid == 0)
      __hip_atomic_store(prog_out, TT / CH, __ATOMIC_RELAXED, __HIP_MEMORY_SCOPE_AGENT);
  }
}

__global__ __launch_bounds__(512, 2) void lstm_fused(
    const float* __restrict__ x, unsigned short* ys,
    const float* __restrict__ Wih0, const float* __restrict__ Whh0, const float* __restrict__ b0,
    const float* __restrict__ Wih1, const float* __restrict__ Whh1, const float* __restrict__ b1,
    const float* __restrict__ Wih2, const float* __restrict__ Whh2, const float* __restrict__ b2,
    float* __restrict__ hT, int* prog)
{
  __shared__ unsigned short x_s[CH * 32 * 128];
  __shared__ unsigned short h_s[2 * 32 * 128];
  __shared__ float b_s[512];
  const int lay = blockIdx.x >> 5;            // 0..2 (32 blocks/layer)
  const int bblk = blockIdx.x & 31;           // 0..31 (32 rows each)
  if (lay == 0) {
    scan_layer<32, true, false>(x_s, h_s, b_s, x, ys, Wih0, Whh0, b0, nullptr,
                                nullptr, &prog[bblk * 16], bblk);
  } else if (lay == 1) {
    scan_layer<128, false, false>(x_s, h_s, b_s, nullptr, ys, Wih1, Whh1, b1, nullptr,
                                  &prog[bblk * 16], &prog[(32 + bblk) * 16], bblk);
  } else {
    scan_layer<128, false, true>(x_s, h_s, b_s, nullptr, ys, Wih2, Whh2, b2, hT,
                                 &prog[(32 + bblk) * 16], nullptr, bblk);
  }
}

__global__ void init_flags(int* prog) {
  prog[threadIdx.x] = 0;
  prog[threadIdx.x + 1024] = 0;
}

// ---------------------------------------------------------------------------
// Head: LN + fc1 + fc2 + 4 heads + reparam + dec1 + dec2 + out. 4 rows/block.
// ---------------------------------------------------------------------------
__global__ __launch_bounds__(256) void head_kernel(
    const float* __restrict__ hT, const float* __restrict__ eps,
    const float* __restrict__ u, const float* __restrict__ choice,
    const float* __restrict__ ln_g, const float* __restrict__ ln_b,
    const float* __restrict__ fc1_W, const float* __restrict__ fc1_b,
    const float* __restrict__ fc2_W, const float* __restrict__ fc2_b,
    const float* __restrict__ mean_W, const float* __restrict__ mean_b,
    const float* __restrict__ logvar_W, const float* __restrict__ logvar_b,
    const float* __restrict__ scale_W, const float* __restrict__ scale_b,
    const float* __restrict__ shape_W, const float* __restrict__ shape_b,
    const float* __restrict__ dec1_W, const float* __restrict__ dec1_b,
    const float* __restrict__ dec2_W, const float* __restrict__ dec2_b,
    const float* __restrict__ out_W, const float* __restrict__ out_b,
    const float* __restrict__ pi_params, float* __restrict__ out)
{
  __shared__ float s_hn[4][128];
  __shared__ float s_a[4][128];
  __shared__ float s_b2[4][64];
  __shared__ float s_z[4][64];
  __shared__ float s_d1[4][128];
  __shared__ float s_d2[4][512];

  const int tid = threadIdx.x;
  const int gr0 = blockIdx.x * 4;

  { // LayerNorm: one wave per row
    const int wvr = tid >> 6, lnn = tid & 63;
    const float v0 = hT[(gr0 + wvr) * 128 + lnn];
    const float v1 = hT[(gr0 + wvr) * 128 + 64 + lnn];
    float s = v0 + v1, s2 = v0 * v0 + v1 * v1;
#pragma unroll
    for (int off = 32; off; off >>= 1) {
      s  += __shfl_xor(s, off, 64);
      s2 += __shfl_xor(s2, off, 64);
    }
    const float mu  = s * (1.f / 128.f);
    const float var = s2 * (1.f / 128.f) - mu * mu;
    const float rs  = rsqrtf(var + 1e-5f);
    s_hn[wvr][lnn]      = (v0 - mu) * rs * ln_g[lnn]      + ln_b[lnn];
    s_hn[wvr][lnn + 64] = (v1 - mu) * rs * ln_g[lnn + 64] + ln_b[lnn + 64];
  }
  __syncthreads();
#pragma unroll
  for (int p = 0; p < 2; ++p) { // fc1 (128x128) + relu
    const int idx = tid + p * 256, row = idx >> 7, col = idx & 127;
    const float* w = fc1_W + col * 128;
    float a = fc1_b[col];
    for (int k = 0; k < 128; k += 4)
      a += s_hn[row][k] * w[k] + s_hn[row][k + 1] * w[k + 1] +
           s_hn[row][k + 2] * w[k + 2] + s_hn[row][k + 3] * w[k + 3];
    s_a[row][col] = fmaxf(a, 0.f);
  }
  __syncthreads();
  { // fc2 (64x128) + relu
    const int row = tid >> 6, col = tid & 63;
    const float* w = fc2_W + col * 128;
    float a = fc2_b[col];
    for (int k = 0; k < 128; ++k) a += s_a[row][k] * w[k];
    s_b2[row][col] = fmaxf(a, 0.f);
  }
  __syncthreads();
  { // 4 heads + reparameterize
    const int row = tid >> 6, c = tid & 63;
    const int gr = gr0 + row;
    float am = mean_b[c], al = logvar_b[c], as_ = scale_b[c], ah = shape_b[c];
    for (int k = 0; k < 64; ++k) {
      const float hv = s_b2[row][k];
      am  += hv * mean_W[c * 64 + k];
      al  += hv * logvar_W[c * 64 + k];
      as_ += hv * scale_W[c * 64 + k];
      ah  += hv * shape_W[c * 64 + k];
    }
    const float zsc = fexp2(as_ * LOG2E);
    const float zsh = fmaxf(ah, 1e-6f);
    out[131072 + gr * 64 + c] = am;
    out[196608 + gr * 64 + c] = al;
    out[262144 + gr * 64 + c] = zsc;
    out[327680 + gr * 64 + c] = zsh;
    const float ev = eps[gr * 64 + c], uv = u[gr * 64 + c], cv = choice[gr];
    const float zg = am + ev * fexp2(0.72134752044448170f * al);  // exp(0.5*logvar)
    const float p0 = pi_params[0], p1 = pi_params[1];
    const float pi0 = 1.f / (1.f + expf(p1 - p0));
    const float tq = -zsh * logf(1.f - uv);                       // expm1: no cancel
    const float zp = zsc * frcp(zsh) * expm1f(tq);
    s_z[row][c] = (cv < pi0) ? zg : zp;
  }
  __syncthreads();
#pragma unroll
  for (int p = 0; p < 2; ++p) { // dec1 (128x64) + relu
    const int idx = tid + p * 256, row = idx >> 7, col = idx & 127;
    const float* w = dec1_W + col * 64;
    float a = dec1_b[col];
    for (int k = 0; k < 64; ++k) a += s_z[row][k] * w[k];
    s_d1[row][col] = fmaxf(a, 0.f);
  }
  __syncthreads();
  for (int o = tid; o < 2000; o += 256) { // dec2 (500x128) + relu
    const int row = o / 500, col = o % 500;
    const float* w = dec2_W + col * 128;
    float a = dec2_b[col];
    for (int k = 0; k < 128; ++k) a += s_d1[row][k] * w[k];
    s_d2[row][col] = fmaxf(a, 0.f);
  }
  __syncthreads();
#pragma unroll
  for (int p = 0; p < 2; ++p) { // out (128x500)
    const int idx = tid + p * 256, row = idx >> 7, col = idx & 127;
    const float* w = out_W + col * 500;
    float a = out_b[col];
    for (int k = 0; k < 500; ++k) a += s_d2[row][k] * w[k];
    out[(gr0 + row) * 128 + col] = a;
  }
}

// ---------------------------------------------------------------------------
extern "C" void kernel_launch(void* const* d_in, const int* in_sizes, int n_in,
                              void* d_out, int out_size, void* d_ws, size_t ws_size,
                              hipStream_t stream) {
  const float* x      = (const float*)d_in[0];
  const float* eps    = (const float*)d_in[1];
  const float* u      = (const float*)d_in[2];
  const float* choice = (const float*)d_in[3];
  const float* Wih0 = (const float*)d_in[4],  *Whh0 = (const float*)d_in[5],  *b0 = (const float*)d_in[6];
  const float* Wih1 = (const float*)d_in[7],  *Whh1 = (const float*)d_in[8],  *b1 = (const float*)d_in[9];
  const float* Wih2 = (const float*)d_in[10], *Whh2 = (const float*)d_in[11], *b2 = (const float*)d_in[12];
  const float* ln_g = (const float*)d_in[13], *ln_b = (const float*)d_in[14];
  const float* fc1_W = (const float*)d_in[15], *fc1_b = (const float*)d_in[16];
  const float* fc2_W = (const float*)d_in[17], *fc2_b = (const float*)d_in[18];
  const float* mean_W = (const float*)d_in[19], *mean_b = (const float*)d_in[20];
  const float* logvar_W = (const float*)d_in[21], *logvar_b = (const float*)d_in[22];
  const float* scale_W = (const float*)d_in[23], *scale_b = (const float*)d_in[24];
  const float* shape_W = (const float*)d_in[25], *shape_b = (const float*)d_in[26];
  const float* dec1_W = (const float*)d_in[27], *dec1_b = (const float*)d_in[28];
  const float* dec2_W = (const float*)d_in[29], *dec2_b = (const float*)d_in[30];
  const float* out_W = (const float*)d_in[31], *out_b = (const float*)d_in[32];
  const float* pi_params = (const float*)d_in[33];

  unsigned short* ys = (unsigned short*)d_ws;                        // 128 MiB
  float* hT  = (float*)((char*)d_ws + (size_t)512 * 1024 * 128 * 2); // 512 KiB
  int*   prog = (int*)((char*)d_ws + (size_t)512 * 1024 * 128 * 2 + (size_t)1024 * 128 * 4);

  init_flags<<<1, 1024, 0, stream>>>(prog);
  lstm_fused<<<96, 512, 0, stream>>>(x, ys, Wih0, Whh0, b0, Wih1, Whh1, b1,
                                     Wih2, Whh2, b2, hT, prog);
  head_kernel<<<256, 256, 0, stream>>>(hT, eps, u, choice, ln_g, ln_b,
      fc1_W, fc1_b, fc2_W, fc2_b, mean_W, mean_b, logvar_W, logvar_b,
      scale_W, scale_b, shape_W, shape_b, dec1_W, dec1_b, dec2_W, dec2_b,
      out_W, out_b, pi_params, (float*)d_out);
}

// Round 13
// 754.487 us; speedup vs baseline: 3.3677x; 1.5321x over previous
//
#include <hip/hip_runtime.h>
#include <math.h>

typedef __attribute__((ext_vector_type(8))) short s16x8;
typedef __attribute__((ext_vector_type(4))) float f32x4;
typedef unsigned long long ull;

constexpr float LOG2E = 1.4426950408889634f;

__device__ __forceinline__ unsigned short f2bf(float f) {
  unsigned int x = __builtin_bit_cast(unsigned int, f);
  x += 0x7fffu + ((x >> 16) & 1u);          // RNE
  return (unsigned short)(x >> 16);
}
__device__ __forceinline__ float fexp2(float x) { return __builtin_amdgcn_exp2f(x); }
__device__ __forceinline__ float frcp(float x)  { return __builtin_amdgcn_rcpf(x); }

#define MFMA16(A, B, Cc) __builtin_amdgcn_mfma_f32_16x16x32_bf16((A), (B), (Cc), 0, 0, 0)

constexpr int TT = 512;
constexpr int NB = 1024;
constexpr int EXS = 132;                    // ex row stride (f32), pad vs 128

// ---------------------------------------------------------------------------
// GATE-SPLIT scan: 16 rows/block, 16 waves (1024 thr), 1 block/CU -> 4
// waves/SIMD (needs <=128 regs/wave incl AGPR -- why weights are halved).
// Wave (cg,gp): cg=wv&7 col-group (16 cells), gp=wv>>3 gate-pair
//   gp0 -> gates i,f : computes A=1+I, B=1+F (2 exp2/cell) -> ex_s
//   gp1 -> gates g,o : owns c-state, finishes cell (G,O,E + 2 rcp) -> h
// Shared-denominator algebra (round-9 validated, absmax identical):
//   c' = [c*(1+I)(1+G) + (G-1)(1+F)] / [(1+F)(1+I)(1+G)]
//   h  = (E-1) / [(1+O)(E+1)],  E = 2^(2*log2e*c')
// gp0 (= tid<512) also does ALL staging/prefetch/deferred ys stores/flags.
// Two barriers/step (B1: ex visible; B2: h(t+1)+x(t+1) visible). Barriers
// measured free (ablation lstmA). Flags: F => ys[0,F) visible at MALL;
// publish F=t-1 at top of step t (prev B2 drained); consumer lag ~3 steps.
// ---------------------------------------------------------------------------
template <int DIN, bool FIRST, bool LAST>
__device__ __forceinline__ void scan_layer(
    unsigned short* x_s,                      // [2][16][DIN] swizzled
    unsigned short* h_s,                      // [2][16][128] swizzled dbuf
    float* ex_s,                              // [2][16][EXS] f32 (A,B planes)
    float* b_s,                               // [512] pre-scaled bias
    const float* __restrict__ xin,            // FIRST: x [B][T][32] f32
    unsigned short* ys,                       // [T][B][128] bf16 pipe (in-place)
    const float* __restrict__ Wih, const float* __restrict__ Whh,
    const float* __restrict__ bias, float* __restrict__ hT,
    int* prog_in, int* prog_out, int bblk)
{
  constexpr int KTX = DIN / 32;               // 1 or 4 x k-tiles
  constexpr int XM  = (DIN == 32) ? 3 : 7;
  const int tid = threadIdx.x;
  const int wv = tid >> 6, ln = tid & 63, l15 = ln & 15, lg = ln >> 4;
  const int cg = wv & 7, gp = wv >> 3;
  const int row0 = bblk * 16;
  const int hcol = cg * 16 + lg * 4;
  const int swzh = (l15 & 7) << 3;
  const int swzx = (l15 & XM) << 3;
  float* exA = ex_s;
  float* exB = ex_s + 16 * EXS;

  // ---- weights: only MY 2 gates -> 64 regs for DIN=128 (halved) ----
  s16x8 bfx[2][KTX], bfh[2][4];
#pragma unroll
  for (int gi = 0; gi < 2; ++gi) {
    const int j = gp * 2 + gi;
    const float scl = (j == 2) ? (2.0f * LOG2E) : (-LOG2E);
    const int n = j * 128 + cg * 16 + l15;
#pragma unroll
    for (int kt = 0; kt < KTX; ++kt) {
      s16x8 f;
#pragma unroll
      for (int e = 0; e < 8; ++e) f[e] = (short)f2bf(Wih[n * DIN + kt * 32 + lg * 8 + e] * scl);
      bfx[gi][kt] = f;
    }
#pragma unroll
    for (int kt = 0; kt < 4; ++kt) {
      s16x8 f;
#pragma unroll
      for (int e = 0; e < 8; ++e) f[e] = (short)f2bf(Whh[n * 128 + kt * 32 + lg * 8 + e] * scl);
      bfh[gi][kt] = f;
    }
  }
  if (tid < 512) b_s[tid] = bias[tid] * ((tid >> 7) == 2 ? 2.0f * LOG2E : -LOG2E);
  for (int i = tid; i < 2 * 16 * 128; i += 1024) h_s[i] = 0;  // h_in(0) = 0

  // staging coords (gp0 threads = tid<512 exactly)
  const int sr = (tid >> 5) & 15, sc = tid & 31;

  // ---- prologue: gp0 stages x(0) into buf0 ----
  int avail = 0;
  if (gp == 0) {
    if (FIRST) {
      const float v = xin[(size_t)(row0 + sr) * (TT * 32) + sc];
      x_s[sr * DIN + (sc ^ ((sr & XM) << 3))] = f2bf(v);
    } else {
      int f;
      do { f = __hip_atomic_load(prog_in, __ATOMIC_RELAXED, __HIP_MEMORY_SCOPE_AGENT); } while (f < 1);
      avail = f;
      const ull v = __hip_atomic_load(
          (ull*)ys + ((size_t)(row0 + sr) * 128 + sc * 4) / 4,
          __ATOMIC_RELAXED, __HIP_MEMORY_SCOPE_AGENT);
      *reinterpret_cast<ull*>(&x_s[sr * DIN + ((sc * 4) ^ ((sr & 7) << 3))]) = v;
    }
  }
  __syncthreads();                            // x(0), h0, b_s visible

  float cst[4] = {0.f, 0.f, 0.f, 0.f};        // gp1 owns c-state

  for (int t = 0; t < TT; ++t) {
    const int tb = t & 1;
    const unsigned short* xbuf = x_s + tb * (16 * DIN);
    const unsigned short* hbuf = h_s + tb * (16 * 128);

    // ---- burst: acc = bias + x(t)@Wih (my 2 gates) ----
    f32x4 acc[2];
    acc[0] = *reinterpret_cast<const f32x4*>(&b_s[(gp * 2 + 0) * 128 + hcol]);
    acc[1] = *reinterpret_cast<const f32x4*>(&b_s[(gp * 2 + 1) * 128 + hcol]);
#pragma unroll
    for (int kt = 0; kt < KTX; ++kt) {
      const s16x8 xf = *reinterpret_cast<const s16x8*>(
          &xbuf[l15 * DIN + ((kt * 32 + lg * 8) ^ swzx)]);
      acc[0] = MFMA16(bfx[0][kt], xf, acc[0]);
      acc[1] = MFMA16(bfx[1][kt], xf, acc[1]);
    }

    // ---- gp0 housekeeping: deferred ys store of y(t-1) + flags + prefetch ----
    int f_new = 0;
    bool pf = false;
    float xrf = 0.f;
    ull xrh = 0ull;
    if (gp == 0) {
      if (!LAST && t > 0) {
        const ull yp = *reinterpret_cast<const ull*>(
            &hbuf[l15 * 128 + (hcol ^ swzh)]);        // y(t-1) == h_in(t)
        __hip_atomic_store(
            (ull*)ys + ((size_t)(t - 1) * (NB * 128) + (size_t)(row0 + l15) * 128 + hcol) / 4,
            yp, __ATOMIC_RELAXED, __HIP_MEMORY_SCOPE_AGENT);
      }
      if (!LAST && tid == 0 && t >= 2)
        __hip_atomic_store(prog_out, t - 1, __ATOMIC_RELAXED, __HIP_MEMORY_SCOPE_AGENT);
      if (t + 1 < TT) {
        if (FIRST) {
          xrf = xin[(size_t)(row0 + sr) * (TT * 32) + (t + 1) * 32 + sc];
          pf = true;
        } else {
          f_new = __hip_atomic_load(prog_in, __ATOMIC_RELAXED, __HIP_MEMORY_SCOPE_AGENT);
          if (avail >= t + 2) {
            xrh = __hip_atomic_load(
                (ull*)ys + ((size_t)(t + 1) * (NB * 128) + (size_t)(row0 + sr) * 128 + sc * 4) / 4,
                __ATOMIC_RELAXED, __HIP_MEMORY_SCOPE_AGENT);
            pf = true;
          }
        }
      }
    }

    // ---- chain: K=128 recurrent MFMA (my 2 gates) ----
#pragma unroll
    for (int kt = 0; kt < 4; ++kt) {
      const s16x8 afr = *reinterpret_cast<const s16x8*>(
          &hbuf[l15 * 128 + ((kt * 32 + lg * 8) ^ swzh)]);
      acc[0] = MFMA16(bfh[0][kt], afr, acc[0]);
      acc[1] = MFMA16(bfh[1][kt], afr, acc[1]);
    }

    // ---- pre-B1 trans ----
    float e0[4], e1[4];
    if (gp == 0) {
#pragma unroll
      for (int r = 0; r < 4; ++r) {
        e0[r] = 1.f + fexp2(fminf(acc[0][r], 29.f));   // A = 1+I
        e1[r] = 1.f + fexp2(fminf(acc[1][r], 29.f));   // B = 1+F
      }
      const f32x4 va = {e0[0], e0[1], e0[2], e0[3]};
      const f32x4 vb = {e1[0], e1[1], e1[2], e1[3]};
      *reinterpret_cast<f32x4*>(&exA[l15 * EXS + hcol]) = va;
      *reinterpret_cast<f32x4*>(&exB[l15 * EXS + hcol]) = vb;
    } else {
#pragma unroll
      for (int r = 0; r < 4; ++r) {
        e0[r] = fexp2(fminf(acc[0][r], 29.f));         // G
        e1[r] = fexp2(fminf(acc[1][r], 29.f));         // O
      }
    }
    __syncthreads();                          // B1: ex visible; hbuf reads done

    if (gp == 0) {
      // slow path: flag shortfall (startup / hiccup)
      if (!FIRST && t + 1 < TT && !pf) {
        int f = f_new;
        while (f < t + 2)
          f = __hip_atomic_load(prog_in, __ATOMIC_RELAXED, __HIP_MEMORY_SCOPE_AGENT);
        f_new = f;
        xrh = __hip_atomic_load(
            (ull*)ys + ((size_t)(t + 1) * (NB * 128) + (size_t)(row0 + sr) * 128 + sc * 4) / 4,
            __ATOMIC_RELAXED, __HIP_MEMORY_SCOPE_AGENT);
      }
      // stage x(t+1) -> buf (t+1)&1
      if (t + 1 < TT) {
        unsigned short* nx = x_s + ((t + 1) & 1) * (16 * DIN);
        if (FIRST) {
          nx[sr * DIN + (sc ^ ((sr & XM) << 3))] = f2bf(xrf);
        } else {
          *reinterpret_cast<ull*>(&nx[sr * DIN + ((sc * 4) ^ ((sr & 7) << 3))]) = xrh;
        }
      }
      if (!FIRST && f_new > avail) avail = f_new;
    } else {
      // ---- finish gates (gp1 owns c) ----
      const f32x4 A  = *reinterpret_cast<const f32x4*>(&exA[l15 * EXS + hcol]);
      const f32x4 Bv = *reinterpret_cast<const f32x4*>(&exB[l15 * EXS + hcol]);
      float hv[4];
#pragma unroll
      for (int r = 0; r < 4; ++r) {
        const float G = e0[r], O = e1[r];
        const float P   = A[r] * (1.f + G);
        const float num = cst[r] * P + (G - 1.f) * Bv[r];
        const float cn  = num * frcp(Bv[r] * P);
        cst[r] = cn;
        const float E = fexp2(fminf(cn * (2.f * LOG2E), 60.f));
        hv[r] = (E - 1.f) * frcp((1.f + O) * (E + 1.f));
      }
      unsigned int plo, phi;
      asm("v_cvt_pk_bf16_f32 %0, %1, %2" : "=v"(plo) : "v"(hv[0]), "v"(hv[1]));
      asm("v_cvt_pk_bf16_f32 %0, %1, %2" : "=v"(phi) : "v"(hv[2]), "v"(hv[3]));
      const ull hpack = (ull)plo | ((ull)phi << 32);
      unsigned short* hnb = h_s + ((t + 1) & 1) * (16 * 128);
      *reinterpret_cast<ull*>(&hnb[l15 * 128 + (hcol ^ swzh)]) = hpack;
      if (LAST && t == TT - 1) {
        f32x4 o = {hv[0], hv[1], hv[2], hv[3]};
        *reinterpret_cast<f32x4*>(&hT[(row0 + l15) * 128 + hcol]) = o;  // f32 for LN
      }
    }
    __syncthreads();                          // B2: h(t+1)+x(t+1) visible; stores drained
  }

  // ---- epilogue: store y(TT-1), drain, publish all ----
  if (!LAST) {
    if (gp == 0) {
      const unsigned short* hb = h_s + (TT & 1) * (16 * 128);  // y(TT-1)
      const ull yp = *reinterpret_cast<const ull*>(&hb[l15 * 128 + (hcol ^ swzh)]);
      __hip_atomic_store(
          (ull*)ys + ((size_t)(TT - 1) * (NB * 128) + (size_t)(row0 + l15) * 128 + hcol) / 4,
          yp, __ATOMIC_RELAXED, __HIP_MEMORY_SCOPE_AGENT);
    }
    asm volatile("s_waitcnt vmcnt(0)" ::: "memory");
    __syncthreads();
    if (tid == 0)
      __hip_atomic_store(prog_out, TT, __ATOMIC_RELAXED, __HIP_MEMORY_SCOPE_AGENT);
  }
}

__global__ __launch_bounds__(1024, 1) void lstm_fused(
    const float* __restrict__ x, unsigned short* ys,
    const float* __restrict__ Wih0, const float* __restrict__ Whh0, const float* __restrict__ b0,
    const float* __restrict__ Wih1, const float* __restrict__ Whh1, const float* __restrict__ b1,
    const float* __restrict__ Wih2, const float* __restrict__ Whh2, const float* __restrict__ b2,
    float* __restrict__ hT, int* prog)
{
  __shared__ unsigned short x_s[2 * 16 * 128];
  __shared__ unsigned short h_s[2 * 16 * 128];
  __shared__ float ex_s[2 * 16 * EXS];
  __shared__ float b_s[512];
  const int lay = blockIdx.x >> 6;
  const int bblk = blockIdx.x & 63;
  if (lay == 0) {
    scan_layer<32, true, false>(x_s, h_s, ex_s, b_s, x, ys, Wih0, Whh0, b0, nullptr,
                                nullptr, &prog[(0 * 64 + bblk) * 16], bblk);
  } else if (lay == 1) {
    scan_layer<128, false, false>(x_s, h_s, ex_s, b_s, nullptr, ys, Wih1, Whh1, b1, nullptr,
                                  &prog[(0 * 64 + bblk) * 16], &prog[(1 * 64 + bblk) * 16], bblk);
  } else {
    scan_layer<128, false, true>(x_s, h_s, ex_s, b_s, nullptr, ys, Wih2, Whh2, b2, hT,
                                 &prog[(1 * 64 + bblk) * 16], nullptr, bblk);
  }
}

__global__ void init_flags(int* prog) {
  prog[threadIdx.x] = 0;
  prog[threadIdx.x + 1024] = 0;
}

// ---------------------------------------------------------------------------
// Head: LN + fc1 + fc2 + 4 heads + reparam + dec1 + dec2 + out. 4 rows/block.
// ---------------------------------------------------------------------------
__global__ __launch_bounds__(256) void head_kernel(
    const float* __restrict__ hT, const float* __restrict__ eps,
    const float* __restrict__ u, const float* __restrict__ choice,
    const float* __restrict__ ln_g, const float* __restrict__ ln_b,
    const float* __restrict__ fc1_W, const float* __restrict__ fc1_b,
    const float* __restrict__ fc2_W, const float* __restrict__ fc2_b,
    const float* __restrict__ mean_W, const float* __restrict__ mean_b,
    const float* __restrict__ logvar_W, const float* __restrict__ logvar_b,
    const float* __restrict__ scale_W, const float* __restrict__ scale_b,
    const float* __restrict__ shape_W, const float* __restrict__ shape_b,
    const float* __restrict__ dec1_W, const float* __restrict__ dec1_b,
    const float* __restrict__ dec2_W, const float* __restrict__ dec2_b,
    const float* __restrict__ out_W, const float* __restrict__ out_b,
    const float* __restrict__ pi_params, float* __restrict__ out)
{
  __shared__ float s_hn[4][128];
  __shared__ float s_a[4][128];
  __shared__ float s_b2[4][64];
  __shared__ float s_z[4][64];
  __shared__ float s_d1[4][128];
  __shared__ float s_d2[4][512];

  const int tid = threadIdx.x;
  const int gr0 = blockIdx.x * 4;

  { // LayerNorm: one wave per row
    const int wvr = tid >> 6, lnn = tid & 63;
    const float v0 = hT[(gr0 + wvr) * 128 + lnn];
    const float v1 = hT[(gr0 + wvr) * 128 + 64 + lnn];
    float s = v0 + v1, s2 = v0 * v0 + v1 * v1;
#pragma unroll
    for (int off = 32; off; off >>= 1) {
      s  += __shfl_xor(s, off, 64);
      s2 += __shfl_xor(s2, off, 64);
    }
    const float mu  = s * (1.f / 128.f);
    const float var = s2 * (1.f / 128.f) - mu * mu;
    const float rs  = rsqrtf(var + 1e-5f);
    s_hn[wvr][lnn]      = (v0 - mu) * rs * ln_g[lnn]      + ln_b[lnn];
    s_hn[wvr][lnn + 64] = (v1 - mu) * rs * ln_g[lnn + 64] + ln_b[lnn + 64];
  }
  __syncthreads();
#pragma unroll
  for (int p = 0; p < 2; ++p) { // fc1 (128x128) + relu
    const int idx = tid + p * 256, row = idx >> 7, col = idx & 127;
    const float* w = fc1_W + col * 128;
    float a = fc1_b[col];
    for (int k = 0; k < 128; k += 4)
      a += s_hn[row][k] * w[k] + s_hn[row][k + 1] * w[k + 1] +
           s_hn[row][k + 2] * w[k + 2] + s_hn[row][k + 3] * w[k + 3];
    s_a[row][col] = fmaxf(a, 0.f);
  }
  __syncthreads();
  { // fc2 (64x128) + relu
    const int row = tid >> 6, col = tid & 63;
    const float* w = fc2_W + col * 128;
    float a = fc2_b[col];
    for (int k = 0; k < 128; ++k) a += s_a[row][k] * w[k];
    s_b2[row][col] = fmaxf(a, 0.f);
  }
  __syncthreads();
  { // 4 heads + reparameterize
    const int row = tid >> 6, c = tid & 63;
    const int gr = gr0 + row;
    float am = mean_b[c], al = logvar_b[c], as_ = scale_b[c], ah = shape_b[c];
    for (int k = 0; k < 64; ++k) {
      const float hv = s_b2[row][k];
      am  += hv * mean_W[c * 64 + k];
      al  += hv * logvar_W[c * 64 + k];
      as_ += hv * scale_W[c * 64 + k];
      ah  += hv * shape_W[c * 64 + k];
    }
    const float zsc = fexp2(as_ * LOG2E);
    const float zsh = fmaxf(ah, 1e-6f);
    out[131072 + gr * 64 + c] = am;
    out[196608 + gr * 64 + c] = al;
    out[262144 + gr * 64 + c] = zsc;
    out[327680 + gr * 64 + c] = zsh;
    const float ev = eps[gr * 64 + c], uv = u[gr * 64 + c], cv = choice[gr];
    const float zg = am + ev * fexp2(0.72134752044448170f * al);  // exp(0.5*logvar)
    const float p0 = pi_params[0], p1 = pi_params[1];
    const float pi0 = 1.f / (1.f + expf(p1 - p0));
    const float tq = -zsh * logf(1.f - uv);                       // expm1: no cancel
    const float zp = zsc * frcp(zsh) * expm1f(tq);
    s_z[row][c] = (cv < pi0) ? zg : zp;
  }
  __syncthreads();
#pragma unroll
  for (int p = 0; p < 2; ++p) { // dec1 (128x64) + relu
    const int idx = tid + p * 256, row = idx >> 7, col = idx & 127;
    const float* w = dec1_W + col * 64;
    float a = dec1_b[col];
    for (int k = 0; k < 64; ++k) a += s_z[row][k] * w[k];
    s_d1[row][col] = fmaxf(a, 0.f);
  }
  __syncthreads();
  for (int o = tid; o < 2000; o += 256) { // dec2 (500x128) + relu
    const int row = o / 500, col = o % 500;
    const float* w = dec2_W + col * 128;
    float a = dec2_b[col];
    for (int k = 0; k < 128; ++k) a += s_d1[row][k] * w[k];
    s_d2[row][col] = fmaxf(a, 0.f);
  }
  __syncthreads();
#pragma unroll
  for (int p = 0; p < 2; ++p) { // out (128x500)
    const int idx = tid + p * 256, row = idx >> 7, col = idx & 127;
    const float* w = out_W + col * 500;
    float a = out_b[col];
    for (int k = 0; k < 500; ++k) a += s_d2[row][k] * w[k];
    out[(gr0 + row) * 128 + col] = a;
  }
}

// ---------------------------------------------------------------------------
extern "C" void kernel_launch(void* const* d_in, const int* in_sizes, int n_in,
                              void* d_out, int out_size, void* d_ws, size_t ws_size,
                              hipStream_t stream) {
  const float* x      = (const float*)d_in[0];
  const float* eps    = (const float*)d_in[1];
  const float* u      = (const float*)d_in[2];
  const float* choice = (const float*)d_in[3];
  const float* Wih0 = (const float*)d_in[4],  *Whh0 = (const float*)d_in[5],  *b0 = (const float*)d_in[6];
  const float* Wih1 = (const float*)d_in[7],  *Whh1 = (const float*)d_in[8],  *b1 = (const float*)d_in[9];
  const float* Wih2 = (const float*)d_in[10], *Whh2 = (const float*)d_in[11], *b2 = (const float*)d_in[12];
  const float* ln_g = (const float*)d_in[13], *ln_b = (const float*)d_in[14];
  const float* fc1_W = (const float*)d_in[15], *fc1_b = (const float*)d_in[16];
  const float* fc2_W = (const float*)d_in[17], *fc2_b = (const float*)d_in[18];
  const float* mean_W = (const float*)d_in[19], *mean_b = (const float*)d_in[20];
  const float* logvar_W = (const float*)d_in[21], *logvar_b = (const float*)d_in[22];
  const float* scale_W = (const float*)d_in[23], *scale_b = (const float*)d_in[24];
  const float* shape_W = (const float*)d_in[25], *shape_b = (const float*)d_in[26];
  const float* dec1_W = (const float*)d_in[27], *dec1_b = (const float*)d_in[28];
  const float* dec2_W = (const float*)d_in[29], *dec2_b = (const float*)d_in[30];
  const float* out_W = (const float*)d_in[31], *out_b = (const float*)d_in[32];
  const float* pi_params = (const float*)d_in[33];

  unsigned short* ys = (unsigned short*)d_ws;                        // 128 MiB
  float* hT  = (float*)((char*)d_ws + (size_t)512 * 1024 * 128 * 2); // 512 KiB
  int*   prog = (int*)((char*)d_ws + (size_t)512 * 1024 * 128 * 2 + (size_t)1024 * 128 * 4);

  init_flags<<<1, 1024, 0, stream>>>(prog);
  lstm_fused<<<192, 1024, 0, stream>>>(x, ys, Wih0, Whh0, b0, Wih1, Whh1, b1,
                                       Wih2, Whh2, b2, hT, prog);
  head_kernel<<<256, 256, 0, stream>>>(hT, eps, u, choice, ln_g, ln_b,
      fc1_W, fc1_b, fc2_W, fc2_b, mean_W, mean_b, logvar_W, logvar_b,
      scale_W, scale_b, shape_W, shape_b, dec1_W, dec1_b, dec2_W, dec2_b,
      out_W, out_b, pi_params, (float*)d_out);
}